// Round 2
// baseline (23593.559 us; speedup 1.0000x reference)
//
#include <hip/hip_runtime.h>

// Pipeline: conv3x3(64->128)+ReLU -> conv3x3(128->32)+ReLU -> bilinear x2 -> conv3x3(32->1)
// N=48, H=W=128 input, output [48,1,256,256] fp32.
//
// Round 2: deliberately NAIVE bisection build. One thread per output pixel,
// pure global-memory reads (L1/L2 do the caching), no LDS, no vector loads,
// scalar stores. Same 4-stage + chunked-workspace skeleton as round 1.
// Purpose: isolate whether round 1's absmax=16 came from the tiled staging
// machinery (then this passes) or from the environment/contract (then this
// fails the same way).

template<int CIN, bool RELU>
__global__ void nconv3x3(const float* __restrict__ in,   // [nc][CIN][H][W]
                         const float* __restrict__ wgt,  // [COUT][CIN][3][3]
                         const float* __restrict__ bias, // [COUT]
                         float* __restrict__ out,        // [nc][COUT][H][W]
                         int H, int W, int COUT)
{
    const int x  = threadIdx.x;          // blockDim.x == W
    const int y  = blockIdx.y;           // gridDim.y == H
    const int co = blockIdx.z % COUT;
    const int n  = blockIdx.z / COUT;

    const float* inN = in + (size_t)n * CIN * H * W;
    const float* wco = wgt + (size_t)co * CIN * 9;

    float acc = bias[co];
    for (int ci = 0; ci < CIN; ci++) {
        const float* ip = inN + (size_t)ci * H * W;
        const float* wp = wco + ci * 9;
        for (int dy = 0; dy < 3; dy++) {
            int yy = y + dy - 1;
            if (yy < 0 || yy >= H) continue;
            for (int dx = 0; dx < 3; dx++) {
                int xx = x + dx - 1;
                if (xx < 0 || xx >= W) continue;
                acc += ip[(size_t)yy * W + xx] * wp[dy * 3 + dx];
            }
        }
    }
    if (RELU) acc = fmaxf(acc, 0.f);
    out[((size_t)n * COUT + co) * H * W + (size_t)y * W + x] = acc;
}

// Bilinear x2 upsample, half-pixel centers (align_corners=False); jax's
// edge-weight renormalization == index clamp. One thread per output pixel.
// in [nc*32][128][128] -> out [nc*32][256][256]
__global__ void nup2x(const float* __restrict__ in, float* __restrict__ out, int total)
{
    int idx = blockIdx.x * 256 + threadIdx.x;
    if (idx >= total) return;
    int X  = idx & 255;
    int Y  = (idx >> 8) & 255;
    int cn = idx >> 16;

    int jx = X >> 1, jy = Y >> 1;
    int jx2 = (X & 1) ? (jx + 1 < 128 ? jx + 1 : 127) : (jx - 1 > 0 ? jx - 1 : 0);
    int jy2 = (Y & 1) ? (jy + 1 < 128 ? jy + 1 : 127) : (jy - 1 > 0 ? jy - 1 : 0);

    const float* p = in + (size_t)cn * 16384;
    float v00 = p[jy  * 128 + jx], v01 = p[jy  * 128 + jx2];
    float v10 = p[jy2 * 128 + jx], v11 = p[jy2 * 128 + jx2];
    // weights: 0.75 on (jx,jy), 0.25 on the clamped neighbor, separable
    out[(size_t)cn * 65536 + (size_t)Y * 256 + X] =
        0.5625f * v00 + 0.1875f * (v01 + v10) + 0.0625f * v11;
}

extern "C" void kernel_launch(void* const* d_in, const int* in_sizes, int n_in,
                              void* d_out, int out_size, void* d_ws, size_t ws_size,
                              hipStream_t stream) {
    const float* x  = (const float*)d_in[0];
    // d_in[1] = to_process (identity arange), d_in[2] = batch_size: the
    // reference computes on all N sites regardless — unused.
    const float* W1 = (const float*)d_in[3];
    const float* b1 = (const float*)d_in[4];
    const float* W2 = (const float*)d_in[5];
    const float* b2 = (const float*)d_in[6];
    const float* W3 = (const float*)d_in[7];
    const float* b3 = (const float*)d_in[8];
    float* out = (float*)d_out;

    const int N = 48;
    // Per image: y1 = 128*128*128 floats (8 MB) in region A; u = 32*256*256
    // floats (8 MB) reuses region A after y1 is dead; y2 = 32*128*128 floats
    // (2 MB) in region B.
    const size_t perA = (size_t)2097152 * sizeof(float);
    const size_t perB = (size_t)524288  * sizeof(float);
    const size_t perImg = perA + perB;   // 10.5 MB

    int chunk = (int)(ws_size / perImg);
    if (chunk < 1) chunk = 1;
    if (chunk > N) chunk = N;

    float* A = (float*)d_ws;
    float* B = (float*)((char*)d_ws + (size_t)chunk * perA);

    for (int n0 = 0; n0 < N; n0 += chunk) {
        int nc = (N - n0 < chunk) ? (N - n0) : chunk;

        // conv1: 64 -> 128, H=W=128, relu
        dim3 g1(1, 128, nc * 128);
        nconv3x3<64, true><<<g1, 128, 0, stream>>>(
            x + (size_t)n0 * 64 * 128 * 128, W1, b1, A, 128, 128, 128);

        // conv2: 128 -> 32, H=W=128, relu
        dim3 g2(1, 128, nc * 32);
        nconv3x3<128, true><<<g2, 128, 0, stream>>>(
            A, W2, b2, B, 128, 128, 32);

        // bilinear x2: B [nc][32][128][128] -> A [nc][32][256][256]
        int total = nc * 32 * 65536;
        nup2x<<<(total + 255) / 256, 256, 0, stream>>>(B, A, total);

        // conv3: 32 -> 1, H=W=256, no relu
        dim3 g4(1, 256, nc * 1);
        nconv3x3<32, false><<<g4, 256, 0, stream>>>(
            A, W3, b3, out + (size_t)n0 * 65536, 256, 256, 1);
    }
}

// Round 3
// 3220.345 us; speedup vs baseline: 7.3264x; 7.3264x over previous
//
#include <hip/hip_runtime.h>

// Pipeline: conv3x3(64->128)+ReLU -> conv3x3(128->32)+ReLU -> bilinear x2 -> conv3x3(32->1)
// N=48, H=W=128 (input), output [48,1,256,256] fp32.
//
// Round 3: tiled fp32 build (round-1 structure) with the round-1 bug fixed:
// conv3x3_c1_k staged 288 weights with `if (tid < 288)` under a 256-thread
// block -> lw[256..287] was uninitialized LDS (absmax 16). Now a strided loop.
//   K1/K2: tile 8 rows x 32 cols, 16 output channels per block.
//          256 thr = r(8) x cg(8) x co_t(4); thread = 4 px x 4 co = 16 acc VGPRs.
//   K3:    bilinear x2 upsample (half-pixel centers, clamp edges == jax renormalized weights)
//   K4:    conv 32->1, tile 16 rows x 64 cols, thread = 4 px.

#define TW 32
#define TH 8
#define CIB 8

template<int CIN, bool RELU>
__global__ __launch_bounds__(256) void conv3x3_k(
    const float* __restrict__ in,   // [nc][CIN][H][W]
    const float* __restrict__ wgt,  // [COUT][CIN][3][3]
    const float* __restrict__ bias, // [COUT]
    float* __restrict__ out,        // [nc][COUT][H][W]
    int H, int W, int COUT, int tilesX)
{
    // inner dim padded 34->36 so row stride = 144B (16B-aligned -> b128-able)
    __shared__ float lx[CIB][TH + 2][TW + 4];
    __shared__ float lw[CIB][9][16];

    const int tid  = threadIdx.x;
    const int co_t = tid & 3;          // 4 co sub-groups
    const int cg   = (tid >> 2) & 7;   // 8 col groups of 4
    const int r    = tid >> 5;         // 8 rows
    const int tileX = blockIdx.x % tilesX;
    const int tileY = blockIdx.x / tilesX;
    const int n  = blockIdx.z;
    const int x0 = tileX * TW, y0 = tileY * TH;
    const int co_base = blockIdx.y * 16;

    const float* inN = in + (size_t)n * CIN * H * W;

    float acc[4][4];
#pragma unroll
    for (int k = 0; k < 4; k++)
#pragma unroll
        for (int c = 0; c < 4; c++) acc[k][c] = 0.f;

    for (int ci0 = 0; ci0 < CIN; ci0 += CIB) {
        // --- stage input tile with halo (zero pad at image borders) ---
        for (int idx = tid; idx < CIB * (TH + 2) * (TW + 2); idx += 256) {
            int col = idx % (TW + 2);
            int t   = idx / (TW + 2);
            int row = t % (TH + 2);
            int ci  = t / (TH + 2);
            int gx = x0 + col - 1, gy = y0 + row - 1;
            float v = 0.f;
            if ((unsigned)gx < (unsigned)W && (unsigned)gy < (unsigned)H)
                v = inN[(size_t)(ci0 + ci) * H * W + gy * W + gx];
            lx[ci][row][col] = v;
        }
        // --- stage weights: lw[ci][tap][co] (LDS writes contiguous) ---
        for (int idx = tid; idx < CIB * 9 * 16; idx += 256) {
            int co = idx & 15;
            int t  = idx >> 4;      // ci*9 + tap
            int tap = t % 9;
            int ci  = t / 9;
            lw[ci][tap][co] = wgt[((size_t)(co_base + co) * CIN + (ci0 + ci)) * 9 + tap];
        }
        __syncthreads();

#pragma unroll
        for (int ci = 0; ci < CIB; ci++) {
#pragma unroll
            for (int dy = 0; dy < 3; dy++) {
                const float* xp = &lx[ci][r + dy][cg * 4];
                float xv[6];
#pragma unroll
                for (int j = 0; j < 6; j++) xv[j] = xp[j];
#pragma unroll
                for (int dx = 0; dx < 3; dx++) {
                    const float* wp = &lw[ci][dy * 3 + dx][co_t * 4];
                    float w0 = wp[0], w1 = wp[1], w2 = wp[2], w3 = wp[3];
#pragma unroll
                    for (int k = 0; k < 4; k++) {
                        float xvv = xv[k + dx];
                        acc[k][0] += xvv * w0;
                        acc[k][1] += xvv * w1;
                        acc[k][2] += xvv * w2;
                        acc[k][3] += xvv * w3;
                    }
                }
            }
        }
        __syncthreads();
    }

#pragma unroll
    for (int c = 0; c < 4; c++) {
        int co = co_base + co_t * 4 + c;
        float bv = bias[co];
        float t0 = acc[0][c] + bv, t1 = acc[1][c] + bv;
        float t2 = acc[2][c] + bv, t3 = acc[3][c] + bv;
        if (RELU) {
            t0 = fmaxf(t0, 0.f); t1 = fmaxf(t1, 0.f);
            t2 = fmaxf(t2, 0.f); t3 = fmaxf(t3, 0.f);
        }
        float4 v; v.x = t0; v.y = t1; v.z = t2; v.w = t3;
        *(float4*)(out + ((size_t)n * COUT + co) * H * W + (size_t)(y0 + r) * W + x0 + cg * 4) = v;
    }
}

// Bilinear x2, half-pixel centers, edge weights renormalized (== index clamp).
// in [nc][32][128][128] -> out [nc][32][256][256]; each thread 4 output cols.
__global__ __launch_bounds__(256) void upsample2x_k(
    const float* __restrict__ in, float* __restrict__ out, int total)
{
    int idx = blockIdx.x * 256 + threadIdx.x;
    if (idx >= total) return;
    int g   = idx & 63;          // col group (4 cols)
    int Y   = (idx >> 6) & 255;
    int c_n = idx >> 14;         // n*32 + c

    int jy  = Y >> 1;
    int jyo = (Y & 1) ? (jy + 1 < 128 ? jy + 1 : 127) : (jy - 1 > 0 ? jy - 1 : 0);

    const float* r0 = in + ((size_t)c_n * 128 + jy)  * 128;
    const float* r1 = in + ((size_t)c_n * 128 + jyo) * 128;
    int xm = g * 2 - 1; if (xm < 0) xm = 0;
    int xp = g * 2 + 2; if (xp > 127) xp = 127;
    int xa = g * 2, xb = g * 2 + 1;

    float m0 = 0.75f * r0[xm] + 0.25f * r1[xm];
    float m1 = 0.75f * r0[xa] + 0.25f * r1[xa];
    float m2 = 0.75f * r0[xb] + 0.25f * r1[xb];
    float m3 = 0.75f * r0[xp] + 0.25f * r1[xp];

    float4 o;
    o.x = 0.75f * m1 + 0.25f * m0;   // X even: 0.25*v[jx-1] + 0.75*v[jx]
    o.y = 0.75f * m1 + 0.25f * m2;   // X odd : 0.75*v[jx] + 0.25*v[jx+1]
    o.z = 0.75f * m2 + 0.25f * m1;
    o.w = 0.75f * m2 + 0.25f * m3;
    *(float4*)(out + ((size_t)c_n * 256 + Y) * 256 + g * 4) = o;
}

// conv3x3 32->1, H=W=256, no relu. Tile 16 rows x 64 cols; thread = 4 px.
__global__ __launch_bounds__(256) void conv3x3_c1_k(
    const float* __restrict__ in,   // [nc][32][256][256]
    const float* __restrict__ wgt,  // [1][32][3][3]
    const float* __restrict__ bias, // [1]
    float* __restrict__ out)        // [nc][256][256]
{
    __shared__ float lx[CIB][18][68];   // 66 used, padded to 68 (272B stride, 16B-aligned)
    __shared__ float lw[32 * 9];

    const int tid = threadIdx.x;
    const int cg  = tid & 15;    // 16 col groups of 4 -> 64 cols
    const int r   = tid >> 4;    // 16 rows
    const int tileX = blockIdx.x & 3;    // 256/64 = 4
    const int tileY = blockIdx.x >> 2;   // 16
    const int n  = blockIdx.z;
    const int x0 = tileX * 64, y0 = tileY * 16;
    const float* inN = in + (size_t)n * 32 * 256 * 256;

    // ROUND-1 BUG WAS HERE: `if (tid < 288)` under blockDim=256 left
    // lw[256..287] uninitialized. Strided loop covers all 288.
    for (int i = tid; i < 288; i += 256) lw[i] = wgt[i];

    float acc[4] = {0.f, 0.f, 0.f, 0.f};
    for (int ci0 = 0; ci0 < 32; ci0 += CIB) {
        for (int idx = tid; idx < CIB * 18 * 66; idx += 256) {
            int col = idx % 66;
            int t   = idx / 66;
            int row = t % 18;
            int ci  = t / 18;
            int gx = x0 + col - 1, gy = y0 + row - 1;
            float v = 0.f;
            if ((unsigned)gx < 256u && (unsigned)gy < 256u)
                v = inN[(size_t)(ci0 + ci) * 65536 + gy * 256 + gx];
            lx[ci][row][col] = v;
        }
        __syncthreads();
#pragma unroll
        for (int ci = 0; ci < CIB; ci++) {
#pragma unroll
            for (int dy = 0; dy < 3; dy++) {
                const float* xp = &lx[ci][r + dy][cg * 4];
                float xv[6];
#pragma unroll
                for (int j = 0; j < 6; j++) xv[j] = xp[j];
                const float* wp = &lw[(ci0 + ci) * 9 + dy * 3];
                float w0 = wp[0], w1 = wp[1], w2 = wp[2];
#pragma unroll
                for (int k = 0; k < 4; k++)
                    acc[k] += xv[k] * w0 + xv[k + 1] * w1 + xv[k + 2] * w2;
            }
        }
        __syncthreads();
    }
    float bv = bias[0];
    float4 o;
    o.x = acc[0] + bv; o.y = acc[1] + bv; o.z = acc[2] + bv; o.w = acc[3] + bv;
    *(float4*)(out + (size_t)n * 65536 + (size_t)(y0 + r) * 256 + x0 + cg * 4) = o;
}

extern "C" void kernel_launch(void* const* d_in, const int* in_sizes, int n_in,
                              void* d_out, int out_size, void* d_ws, size_t ws_size,
                              hipStream_t stream) {
    const float* x  = (const float*)d_in[0];
    // d_in[1] = to_process (identity), d_in[2] = batch_size : not needed, the
    // reference computes on all N sites regardless.
    const float* W1 = (const float*)d_in[3];
    const float* b1 = (const float*)d_in[4];
    const float* W2 = (const float*)d_in[5];
    const float* b2 = (const float*)d_in[6];
    const float* W3 = (const float*)d_in[7];
    const float* b3 = (const float*)d_in[8];
    float* out = (float*)d_out;

    const int N = 48;
    // Per image: y1 = 128*128*128 floats = 8 MB ; u = 32*256*256 floats = 8 MB (same size,
    // u reuses y1's region A). y2 = 32*128*128 floats = 2 MB (region B).
    const size_t perA = (size_t)2097152 * sizeof(float);   // 8 MB
    const size_t perB = (size_t)524288  * sizeof(float);   // 2 MB
    const size_t perImg = perA + perB;                     // 10.5 MB

    int chunk = (int)(ws_size / perImg);
    if (chunk < 1) chunk = 1;
    if (chunk > N) chunk = N;

    float* A = (float*)d_ws;                                   // y1, then u
    float* B = (float*)((char*)d_ws + (size_t)chunk * perA);   // y2

    for (int n0 = 0; n0 < N; n0 += chunk) {
        int nc = (N - n0 < chunk) ? (N - n0) : chunk;

        dim3 g1(64, 8, nc);   // 4x16 tiles, 128/16 co-groups
        conv3x3_k<64, true><<<g1, 256, 0, stream>>>(
            x + (size_t)n0 * 64 * 128 * 128, W1, b1, A, 128, 128, 128, 4);

        dim3 g2(64, 2, nc);   // 32/16 co-groups
        conv3x3_k<128, true><<<g2, 256, 0, stream>>>(
            A, W2, b2, B, 128, 128, 32, 4);

        int total = nc * 32 * 256 * 64;
        upsample2x_k<<<(total + 255) / 256, 256, 0, stream>>>(B, A, total);

        dim3 g4(64, 1, nc);   // 4x16 tiles of 64x16
        conv3x3_c1_k<<<g4, 256, 0, stream>>>(
            A, W3, b3, out + (size_t)n0 * 65536);
    }
}

// Round 4
// 892.710 us; speedup vs baseline: 26.4291x; 3.6074x over previous
//
#include <hip/hip_runtime.h>

// Pipeline: conv3x3(64->128)+ReLU -> conv3x3(128->32)+ReLU -> bilinear x2 -> conv3x3(32->1)
// N=48, H=W=128 input, out [48,1,256,256] fp32.
//
// Round 4: fp16 MFMA implicit-GEMM.
//  - repack_x: x fp32 NCHW -> xh fp16 NHWC (ci contiguous = MFMA K-dim contiguous)
//  - repack_w: W fp32 [co][ci][tap] -> fp16 [tap][co][ci]
//  - conv1: 32x32x16_f16 MFMA. block=128co x (32w x 4h px), 4 waves = 2co x 2px splits,
//           wave = 64co x 64px. K = 9 taps x 4 ci-chunks(16). A from global (L1-resident),
//           B from LDS tile [6][34][72pad] (pitch 72 halves -> optimal 8-lane/bank-group b128).
//  - conv2: 16x16x32_f16 MFMA. block=32co x (16w x 16h px), ci staged in halves of 64.
//  - upsample: packed-fp16 bilinear (half-pixel centers, clamp edge == jax renorm).
//  - conv3: 32->1 via v_dot2_f32_f16, LDS tile, fp32 out.
// Workspace: [A: xh 96MB then uh 192MB][B: y1h 192MB][C: y2h 48MB][W: ~0.25MB] = 432MB.
// (round 3 ran chunk=48 => ws_size >= 504MB)

typedef _Float16 half_t;
typedef _Float16 half2_t __attribute__((ext_vector_type(2)));
typedef _Float16 half4_t __attribute__((ext_vector_type(4)));
typedef _Float16 half8   __attribute__((ext_vector_type(8)));
typedef float    floatx4  __attribute__((ext_vector_type(4)));
typedef float    floatx16 __attribute__((ext_vector_type(16)));

// ---------- pre-pass: weights fp32 [co][ci][3][3] -> fp16 [tap][co][ci] ----------
__global__ __launch_bounds__(256) void repack_w(
    const float* __restrict__ W1, const float* __restrict__ W2,
    const float* __restrict__ W3, half_t* __restrict__ wh1,
    half_t* __restrict__ wh2, half_t* __restrict__ wh3)
{
    int idx = blockIdx.x * 256 + threadIdx.x;
    if (idx < 73728) {                       // wh1[tap][128][64]
        int ci = idx & 63, co = (idx >> 6) & 127, tap = idx >> 13;
        wh1[idx] = (half_t)W1[(co * 64 + ci) * 9 + tap];
    } else if (idx < 110592) {               // wh2[tap][32][128]
        int j = idx - 73728;
        int ci = j & 127, co = (j >> 7) & 31, tap = j >> 12;
        wh2[j] = (half_t)W2[(co * 128 + ci) * 9 + tap];
    } else if (idx < 110880) {               // wh3[tap][32]
        int j = idx - 110592;
        int ci = j & 31, tap = j >> 5;
        wh3[j] = (half_t)W3[ci * 9 + tap];
    }
}

// ---------- pre-pass: x fp32 [48][64][128][128] -> xh fp16 NHWC [48][128][128][64] ----------
__global__ __launch_bounds__(256) void repack_x(
    const float* __restrict__ x, half_t* __restrict__ xh)
{
    const int tid = threadIdx.x;
    const int px = tid & 127, rr = tid >> 7;
    const int y = blockIdx.x * 2 + rr;
    const int n = blockIdx.y;
    const float* xn = x + (size_t)n * 64 * 16384 + (size_t)y * 128 + px;
    half2_t hb[32];
#pragma unroll
    for (int c2 = 0; c2 < 32; ++c2) {
        float f0 = xn[(size_t)(2 * c2) * 16384];
        float f1 = xn[(size_t)(2 * c2 + 1) * 16384];
        half2_t h; h.x = (half_t)f0; h.y = (half_t)f1;
        hb[c2] = h;
    }
    half_t* op = xh + (((size_t)n * 128 + y) * 128 + px) * 64;
#pragma unroll
    for (int k = 0; k < 8; ++k)
        *(half8*)(op + k * 8) = *(half8*)(&hb[k * 4]);
}

// ---------- conv1: 64->128, relu, 32x32x16 MFMA ----------
// grid (4, 32, 48): x-tiles of 32, y-tiles of 4. 256 thr = 4 waves:
// wave = (wco 0..1: co half) x (wpx 0..1: px-row half). wave tile 64co x (32w x 2h).
__global__ __launch_bounds__(256, 4) void conv1_mfma(
    const half_t* __restrict__ xh,   // [n][128][128][64]
    const half_t* __restrict__ wh,   // [9][128][64]
    const float*  __restrict__ bias, // [128]
    half_t* __restrict__ y1h)        // [n][128][128][128]
{
    __shared__ half_t lx[6 * 34 * 72];   // rows(+halo) x cols(+halo) x ci(64 pad 72)
    const int tid  = threadIdx.x;
    const int lane = tid & 63;
    const int wave = tid >> 6;
    const int l31 = lane & 31, lq = lane >> 5;
    const int wco = wave >> 1, wpx = wave & 1;
    const int x0 = blockIdx.x * 32, y0 = blockIdx.y * 4;
    const int n = blockIdx.z;
    const half_t* xn = xh + (size_t)n * (128 * 128 * 64);

    // stage x tile rows y0-1..y0+4, cols x0-1..x0+32 (zero pad at borders)
    for (int idx = tid; idx < 6 * 34 * 8; idx += 256) {
        int ch = idx & 7;
        int col = (idx >> 3) % 34;
        int row = (idx >> 3) / 34;
        int gx = x0 - 1 + col, gy = y0 - 1 + row;
        half8 v = {};
        if ((unsigned)gx < 128u && (unsigned)gy < 128u)
            v = *(const half8*)(xn + ((size_t)gy * 128 + gx) * 64 + ch * 8);
        *(half8*)(&lx[(row * 34 + col) * 72 + ch * 8]) = v;
    }
    __syncthreads();

    floatx16 acc00 = {}, acc01 = {}, acc10 = {}, acc11 = {};

#pragma unroll
    for (int tap = 0; tap < 9; ++tap) {
        const int dy = tap / 3, dx = tap % 3;   // compile-time under unroll
        // A: lane holds W[co = wco*64 + mf*32 + l31][k = kc*16 + lq*8 + j]
        const half_t* wt = wh + tap * (128 * 64) + (wco * 64 + l31) * 64 + lq * 8;
        // B: lane holds X[k][px = l31]; input row = (wpx*2 + nf) + dy, col = l31 + dx
        const half_t* bp = &lx[((wpx * 2 + dy) * 34 + l31 + dx) * 72 + lq * 8];
#pragma unroll
        for (int kc = 0; kc < 4; ++kc) {
            half8 a0 = *(const half8*)(wt + kc * 16);
            half8 a1 = *(const half8*)(wt + 32 * 64 + kc * 16);
            half8 b0 = *(const half8*)(bp + kc * 16);
            half8 b1 = *(const half8*)(bp + 34 * 72 + kc * 16);
            acc00 = __builtin_amdgcn_mfma_f32_32x32x16_f16(a0, b0, acc00, 0, 0, 0);
            acc01 = __builtin_amdgcn_mfma_f32_32x32x16_f16(a0, b1, acc01, 0, 0, 0);
            acc10 = __builtin_amdgcn_mfma_f32_32x32x16_f16(a1, b0, acc10, 0, 0, 0);
            acc11 = __builtin_amdgcn_mfma_f32_32x32x16_f16(a1, b1, acc11, 0, 0, 0);
        }
    }

    // C/D 32x32: col(px) = l31, row(co local) = (reg&3) + 8*(reg>>2) + 4*lq
#pragma unroll
    for (int mf = 0; mf < 2; ++mf) {
        int co0 = wco * 64 + mf * 32 + lq * 4;
#pragma unroll
        for (int nf = 0; nf < 2; ++nf) {
            floatx16 A = (mf == 0) ? (nf == 0 ? acc00 : acc01)
                                   : (nf == 0 ? acc10 : acc11);
            int oy = y0 + wpx * 2 + nf, ox = x0 + l31;
            half_t* op = y1h + (((size_t)n * 128 + oy) * 128 + ox) * 128 + co0;
#pragma unroll
            for (int g = 0; g < 4; ++g) {
                floatx4 bv = *(const floatx4*)(bias + co0 + 8 * g);
                half4_t o;
                o.x = (half_t)fmaxf(A[4 * g + 0] + bv.x, 0.f);
                o.y = (half_t)fmaxf(A[4 * g + 1] + bv.y, 0.f);
                o.z = (half_t)fmaxf(A[4 * g + 2] + bv.z, 0.f);
                o.w = (half_t)fmaxf(A[4 * g + 3] + bv.w, 0.f);
                *(half4_t*)(op + 8 * g) = o;
            }
        }
    }
}

// ---------- conv2: 128->32, relu, 16x16x32 MFMA ----------
// grid (8, 8, 48): block = 16w x 16h px, all 32 co. 4 waves = 4 row-quads.
// ci staged in halves of 64 (LDS 46.7 KB).
__global__ __launch_bounds__(256, 3) void conv2_mfma(
    const half_t* __restrict__ y1h,  // [n][128][128][128]
    const half_t* __restrict__ wh,   // [9][32][128]
    const float*  __restrict__ bias, // [32]
    half_t* __restrict__ y2h)        // [n][128][128][32]
{
    __shared__ half_t lx[18 * 18 * 72];
    const int tid  = threadIdx.x;
    const int lane = tid & 63;
    const int wave = tid >> 6;
    const int l15 = lane & 15, quad = lane >> 4;
    const int x0 = blockIdx.x * 16, y0 = blockIdx.y * 16;
    const int n = blockIdx.z;
    const half_t* yn = y1h + (size_t)n * (128 * 128 * 128);

    floatx4 acc[2][4] = {};

    for (int h = 0; h < 2; ++h) {
        for (int idx = tid; idx < 18 * 18 * 8; idx += 256) {
            int ch = idx & 7;
            int col = (idx >> 3) % 18;
            int row = (idx >> 3) / 18;
            int gx = x0 - 1 + col, gy = y0 - 1 + row;
            half8 v = {};
            if ((unsigned)gx < 128u && (unsigned)gy < 128u)
                v = *(const half8*)(yn + ((size_t)gy * 128 + gx) * 128 + h * 64 + ch * 8);
            *(half8*)(&lx[(row * 18 + col) * 72 + ch * 8]) = v;
        }
        __syncthreads();
#pragma unroll
        for (int tap = 0; tap < 9; ++tap) {
            const int dy = tap / 3, dx = tap % 3;
            // A: co = mf*16 + l15, k = h*64 + kc*32 + quad*8 + j
            const half_t* wt = wh + tap * (32 * 128) + l15 * 128 + h * 64 + quad * 8;
#pragma unroll
            for (int kc = 0; kc < 2; ++kc) {
                half8 a0 = *(const half8*)(wt + kc * 32);
                half8 a1 = *(const half8*)(wt + 16 * 128 + kc * 32);
                const half_t* bp = &lx[((wave * 4 + dy) * 18 + l15 + dx) * 72 + kc * 32 + quad * 8];
#pragma unroll
                for (int nf = 0; nf < 4; ++nf) {
                    half8 b = *(const half8*)(bp + nf * (18 * 72));
                    acc[0][nf] = __builtin_amdgcn_mfma_f32_16x16x32_f16(a0, b, acc[0][nf], 0, 0, 0);
                    acc[1][nf] = __builtin_amdgcn_mfma_f32_16x16x32_f16(a1, b, acc[1][nf], 0, 0, 0);
                }
            }
        }
        __syncthreads();
    }

    // C/D 16x16: col(px)=l15, row(co local)=quad*4+reg
#pragma unroll
    for (int mf = 0; mf < 2; ++mf) {
        int co0 = mf * 16 + quad * 4;
        floatx4 bv = *(const floatx4*)(bias + co0);
#pragma unroll
        for (int nf = 0; nf < 4; ++nf) {
            int oy = y0 + wave * 4 + nf, ox = x0 + l15;
            floatx4 A = acc[mf][nf];
            half4_t o;
            o.x = (half_t)fmaxf(A.x + bv.x, 0.f);
            o.y = (half_t)fmaxf(A.y + bv.y, 0.f);
            o.z = (half_t)fmaxf(A.z + bv.z, 0.f);
            o.w = (half_t)fmaxf(A.w + bv.w, 0.f);
            *(half4_t*)(y2h + (((size_t)n * 128 + oy) * 128 + ox) * 32 + co0) = o;
        }
    }
}

// ---------- bilinear x2 (half-pixel centers, clamp edge), NHWC fp16 ----------
__global__ __launch_bounds__(256) void upsample_k(
    const half_t* __restrict__ y2h, half_t* __restrict__ uh)
{
    int idx = blockIdx.x * 256 + threadIdx.x;
    int X = idx & 255, Y = (idx >> 8) & 255, n = idx >> 16;
    int jx = X >> 1, jy = Y >> 1;
    int jxo = (X & 1) ? (jx < 127 ? jx + 1 : 127) : (jx > 0 ? jx - 1 : 0);
    int jyo = (Y & 1) ? (jy < 127 ? jy + 1 : 127) : (jy > 0 ? jy - 1 : 0);
    const half_t* base = y2h + (size_t)n * (128 * 128 * 32);
    const half_t* p00 = base + ((size_t)jy  * 128 + jx ) * 32;
    const half_t* p01 = base + ((size_t)jy  * 128 + jxo) * 32;
    const half_t* p10 = base + ((size_t)jyo * 128 + jx ) * 32;
    const half_t* p11 = base + ((size_t)jyo * 128 + jxo) * 32;
    half_t* op = uh + (((size_t)n * 256 + Y) * 256 + X) * 32;
#pragma unroll
    for (int c = 0; c < 4; ++c) {
        half8 v00 = *(const half8*)(p00 + c * 8);
        half8 v01 = *(const half8*)(p01 + c * 8);
        half8 v10 = *(const half8*)(p10 + c * 8);
        half8 v11 = *(const half8*)(p11 + c * 8);
        half8 o = v00 * (half_t)0.5625f + (v01 + v10) * (half_t)0.1875f
                + v11 * (half_t)0.0625f;
        *(half8*)(op + c * 8) = o;
    }
}

// ---------- conv3: 32->1, fp32 out, v_dot2_f32_f16 ----------
// grid (8, 32, 48): block = 32w x 8h out px, thread = 1 px.
__global__ __launch_bounds__(256) void conv3_k(
    const half_t* __restrict__ uh,   // [n][256][256][32]
    const half_t* __restrict__ wh3,  // [9][32]
    const float*  __restrict__ bias, // [1]
    float* __restrict__ out)         // [n][256][256]
{
    __shared__ half_t lu[10 * 34 * 40];   // ci pitch 32 pad 40 (bank spread)
    const int tid = threadIdx.x;
    const int c = tid & 31, r = tid >> 5;
    const int x0 = blockIdx.x * 32, y0 = blockIdx.y * 8;
    const int n = blockIdx.z;
    const half_t* un = uh + (size_t)n * (256 * 256 * 32);

    for (int idx = tid; idx < 10 * 34 * 4; idx += 256) {
        int ch = idx & 3;
        int col = (idx >> 2) % 34;
        int row = (idx >> 2) / 34;
        int gx = x0 - 1 + col, gy = y0 - 1 + row;
        half8 v = {};
        if ((unsigned)gx < 256u && (unsigned)gy < 256u)
            v = *(const half8*)(un + ((size_t)gy * 256 + gx) * 32 + ch * 8);
        *(half8*)(&lu[(row * 34 + col) * 40 + ch * 8]) = v;
    }
    __syncthreads();

    float acc = 0.f;
#pragma unroll
    for (int tap = 0; tap < 9; ++tap) {
        const int dy = tap / 3, dx = tap % 3;
        const half_t* lp = &lu[((r + dy) * 34 + c + dx) * 40];
        const half_t* wp = wh3 + tap * 32;
#pragma unroll
        for (int cc = 0; cc < 4; ++cc) {
            half8 v = *(const half8*)(lp + cc * 8);
            half8 w = *(const half8*)(wp + cc * 8);
            acc = __builtin_amdgcn_fdot2(__builtin_shufflevector(v, v, 0, 1),
                                         __builtin_shufflevector(w, w, 0, 1), acc, false);
            acc = __builtin_amdgcn_fdot2(__builtin_shufflevector(v, v, 2, 3),
                                         __builtin_shufflevector(w, w, 2, 3), acc, false);
            acc = __builtin_amdgcn_fdot2(__builtin_shufflevector(v, v, 4, 5),
                                         __builtin_shufflevector(w, w, 4, 5), acc, false);
            acc = __builtin_amdgcn_fdot2(__builtin_shufflevector(v, v, 6, 7),
                                         __builtin_shufflevector(w, w, 6, 7), acc, false);
        }
    }
    out[((size_t)n * 256 + (y0 + r)) * 256 + x0 + c] = acc + bias[0];
}

extern "C" void kernel_launch(void* const* d_in, const int* in_sizes, int n_in,
                              void* d_out, int out_size, void* d_ws, size_t ws_size,
                              hipStream_t stream) {
    const float* x  = (const float*)d_in[0];
    // d_in[1] = to_process (identity arange), d_in[2] = batch_size: unused.
    const float* W1 = (const float*)d_in[3];
    const float* b1 = (const float*)d_in[4];
    const float* W2 = (const float*)d_in[5];
    const float* b2 = (const float*)d_in[6];
    const float* W3 = (const float*)d_in[7];
    const float* b3 = (const float*)d_in[8];
    float* out = (float*)d_out;

    char* ws = (char*)d_ws;
    half_t* xh  = (half_t*)ws;                   // 96 MB, region A
    half_t* uh  = (half_t*)ws;                   // 192 MB, region A (xh dead by then)
    half_t* y1h = (half_t*)(ws + 201326592ull);  // 192 MB, region B
    half_t* y2h = (half_t*)(ws + 402653184ull);  // 48 MB,  region C
    half_t* wh1 = (half_t*)(ws + 452984832ull);  // 9*128*64
    half_t* wh2 = wh1 + 73728;                   // 9*32*128
    half_t* wh3 = wh2 + 36864;                   // 9*32

    repack_w<<<434, 256, 0, stream>>>(W1, W2, W3, wh1, wh2, wh3);
    repack_x<<<dim3(64, 48), 256, 0, stream>>>(x, xh);
    conv1_mfma<<<dim3(4, 32, 48), 256, 0, stream>>>(xh, wh1, b1, y1h);
    conv2_mfma<<<dim3(8, 8, 48), 256, 0, stream>>>(y1h, wh2, b2, y2h);
    upsample_k<<<12288, 256, 0, stream>>>(y2h, uh);
    conv3_k<<<dim3(8, 32, 48), 256, 0, stream>>>(uh, wh3, b3, out);
}

// Round 5
// 832.163 us; speedup vs baseline: 28.3521x; 1.0728x over previous
//
#include <hip/hip_runtime.h>

// Pipeline: conv3x3(64->128)+ReLU -> conv3x3(128->32)+ReLU -> bilinear x2 -> conv3x3(32->1)
// N=48, H=W=128 input, out [48,1,256,256] fp32.
//
// Round 5: fp16 MFMA implicit-GEMM, latency fix.
//  Round-4 conv1 was latency-bound (MfmaUtil 17%, VALUBusy 8%, occ 43%, VGPR 52):
//  __launch_bounds__(256,4) choked the register file -> no load pipelining, and the
//  wave tile (4 MFMA per 4 loads) was too small.
//  - conv1: block 128co x 256px (32w x 8h), wave 64co x 128px, acc[2][4] fx16 (128 AGPR),
//           8 MFMA per {2 global A + 4 LDS B} loads. __launch_bounds__(256,2).
//  - conv2: block 32co x 512px (32w x 16h), ci staged in quarters (LDS 49KB),
//           wave 32co x 128px, acc[2][8] fx4 (64 AGPR), 16 MFMA per {2+8} loads.
//  - repack_x / repack_w / upsample / conv3 unchanged (round-4 verified).
// Workspace: [A: xh 96MB then uh 192MB][B: y1h 192MB][C: y2h 48MB][W] = 432MB.

typedef _Float16 half_t;
typedef _Float16 half2_t __attribute__((ext_vector_type(2)));
typedef _Float16 half4_t __attribute__((ext_vector_type(4)));
typedef _Float16 half8   __attribute__((ext_vector_type(8)));
typedef float    floatx4  __attribute__((ext_vector_type(4)));
typedef float    floatx16 __attribute__((ext_vector_type(16)));

// ---------- pre-pass: weights fp32 [co][ci][3][3] -> fp16 [tap][co][ci] ----------
__global__ __launch_bounds__(256) void repack_w(
    const float* __restrict__ W1, const float* __restrict__ W2,
    const float* __restrict__ W3, half_t* __restrict__ wh1,
    half_t* __restrict__ wh2, half_t* __restrict__ wh3)
{
    int idx = blockIdx.x * 256 + threadIdx.x;
    if (idx < 73728) {                       // wh1[tap][128][64]
        int ci = idx & 63, co = (idx >> 6) & 127, tap = idx >> 13;
        wh1[idx] = (half_t)W1[(co * 64 + ci) * 9 + tap];
    } else if (idx < 110592) {               // wh2[tap][32][128]
        int j = idx - 73728;
        int ci = j & 127, co = (j >> 7) & 31, tap = j >> 12;
        wh2[j] = (half_t)W2[(co * 128 + ci) * 9 + tap];
    } else if (idx < 110880) {               // wh3[tap][32]
        int j = idx - 110592;
        int ci = j & 31, tap = j >> 5;
        wh3[j] = (half_t)W3[ci * 9 + tap];
    }
}

// ---------- pre-pass: x fp32 [48][64][128][128] -> xh fp16 NHWC [48][128][128][64] ----------
__global__ __launch_bounds__(256) void repack_x(
    const float* __restrict__ x, half_t* __restrict__ xh)
{
    const int tid = threadIdx.x;
    const int px = tid & 127, rr = tid >> 7;
    const int y = blockIdx.x * 2 + rr;
    const int n = blockIdx.y;
    const float* xn = x + (size_t)n * 64 * 16384 + (size_t)y * 128 + px;
    half2_t hb[32];
#pragma unroll
    for (int c2 = 0; c2 < 32; ++c2) {
        float f0 = xn[(size_t)(2 * c2) * 16384];
        float f1 = xn[(size_t)(2 * c2 + 1) * 16384];
        half2_t h; h.x = (half_t)f0; h.y = (half_t)f1;
        hb[c2] = h;
    }
    half_t* op = xh + (((size_t)n * 128 + y) * 128 + px) * 64;
#pragma unroll
    for (int k = 0; k < 8; ++k)
        *(half8*)(op + k * 8) = *(half8*)(&hb[k * 4]);
}

// ---------- conv1: 64->128, relu, 32x32x16 MFMA ----------
// grid (4, 16, 48). block = 128co x (32w x 8h). 4 waves = (wco 0..1) x (wpx 0..1).
// wave = 64co x (32w x 4h) -> acc[2][4] floatx16 (128 AGPR), 8 MFMA per 6 loads.
__global__ __launch_bounds__(256, 2) void conv1_mfma(
    const half_t* __restrict__ xh,   // [n][128][128][64]
    const half_t* __restrict__ wh,   // [9][128][64]
    const float*  __restrict__ bias, // [128]
    half_t* __restrict__ y1h)        // [n][128][128][128]
{
    __shared__ half_t lx[10 * 34 * 72];   // rows(8+2) x cols(32+2) x ci(64 pad 72)
    const int tid  = threadIdx.x;
    const int lane = tid & 63;
    const int wave = tid >> 6;
    const int l31 = lane & 31, lq = lane >> 5;
    const int wco = wave >> 1, wpx = wave & 1;
    const int x0 = blockIdx.x * 32, y0 = blockIdx.y * 8;
    const int n = blockIdx.z;
    const half_t* xn = xh + (size_t)n * (128 * 128 * 64);

    // stage x tile rows y0-1..y0+8, cols x0-1..x0+32 (zero pad at borders)
    for (int idx = tid; idx < 10 * 34 * 8; idx += 256) {
        int ch = idx & 7;
        int col = (idx >> 3) % 34;
        int row = (idx >> 3) / 34;
        int gx = x0 - 1 + col, gy = y0 - 1 + row;
        half8 v = {};
        if ((unsigned)gx < 128u && (unsigned)gy < 128u)
            v = *(const half8*)(xn + ((size_t)gy * 128 + gx) * 64 + ch * 8);
        *(half8*)(&lx[(row * 34 + col) * 72 + ch * 8]) = v;
    }
    __syncthreads();

    floatx16 acc[2][4] = {};

#pragma unroll
    for (int tap = 0; tap < 9; ++tap) {
        const int dy = tap / 3, dx = tap % 3;   // compile-time under unroll
        // A: lane holds W[co = wco*64 + mf*32 + l31][k = kc*16 + lq*8 + j]
        const half_t* wt = wh + tap * (128 * 64) + (wco * 64 + l31) * 64 + lq * 8;
        // B: lane holds X[k][px]; wave rows wpx*4+nf, col l31 (+halo shift dx,dy)
        const half_t* bp = &lx[((wpx * 4 + dy) * 34 + l31 + dx) * 72 + lq * 8];
#pragma unroll
        for (int kc = 0; kc < 4; ++kc) {
            half8 a0 = *(const half8*)(wt + kc * 16);
            half8 a1 = *(const half8*)(wt + 32 * 64 + kc * 16);
            half8 b[4];
#pragma unroll
            for (int nf = 0; nf < 4; ++nf)
                b[nf] = *(const half8*)(bp + nf * (34 * 72) + kc * 16);
#pragma unroll
            for (int nf = 0; nf < 4; ++nf) {
                acc[0][nf] = __builtin_amdgcn_mfma_f32_32x32x16_f16(a0, b[nf], acc[0][nf], 0, 0, 0);
                acc[1][nf] = __builtin_amdgcn_mfma_f32_32x32x16_f16(a1, b[nf], acc[1][nf], 0, 0, 0);
            }
        }
    }

    // C/D 32x32: col(px) = l31, row(co local) = (reg&3) + 8*(reg>>2) + 4*lq
#pragma unroll
    for (int mf = 0; mf < 2; ++mf) {
        int co0 = wco * 64 + mf * 32 + lq * 4;
#pragma unroll
        for (int nf = 0; nf < 4; ++nf) {
            floatx16 A = acc[mf][nf];
            int oy = y0 + wpx * 4 + nf, ox = x0 + l31;
            half_t* op = y1h + (((size_t)n * 128 + oy) * 128 + ox) * 128 + co0;
#pragma unroll
            for (int g = 0; g < 4; ++g) {
                floatx4 bv = *(const floatx4*)(bias + co0 + 8 * g);
                half4_t o;
                o.x = (half_t)fmaxf(A[4 * g + 0] + bv.x, 0.f);
                o.y = (half_t)fmaxf(A[4 * g + 1] + bv.y, 0.f);
                o.z = (half_t)fmaxf(A[4 * g + 2] + bv.z, 0.f);
                o.w = (half_t)fmaxf(A[4 * g + 3] + bv.w, 0.f);
                *(half4_t*)(op + 8 * g) = o;
            }
        }
    }
}

// ---------- conv2: 128->32, relu, 16x16x32 MFMA ----------
// grid (4, 8, 48). block = 32co x (32w x 16h px). 4 waves = 4 row-quads.
// ci staged in quarters of 32 (LDS 49KB). wave = 32co x 128px:
// acc[2][8] floatx4 (64 AGPR), 16 MFMA per {2 global A + 8 LDS B} loads.
__global__ __launch_bounds__(256, 3) void conv2_mfma(
    const half_t* __restrict__ y1h,  // [n][128][128][128]
    const half_t* __restrict__ wh,   // [9][32][128]
    const float*  __restrict__ bias, // [32]
    half_t* __restrict__ y2h)        // [n][128][128][32]
{
    __shared__ half_t lx[18 * 34 * 40];   // rows(16+2) x cols(32+2) x ci(32 pad 40)
    const int tid  = threadIdx.x;
    const int lane = tid & 63;
    const int w    = tid >> 6;
    const int l15 = lane & 15, quad = lane >> 4;
    const int x0 = blockIdx.x * 32, y0 = blockIdx.y * 16;
    const int n = blockIdx.z;
    const half_t* yn = y1h + (size_t)n * (128 * 128 * 128);

    floatx4 acc[2][8] = {};

    for (int h = 0; h < 4; ++h) {        // ci quarters of 32
        for (int idx = tid; idx < 18 * 34 * 4; idx += 256) {
            int ch = idx & 3;
            int col = (idx >> 2) % 34;
            int row = (idx >> 2) / 34;
            int gx = x0 - 1 + col, gy = y0 - 1 + row;
            half8 v = {};
            if ((unsigned)gx < 128u && (unsigned)gy < 128u)
                v = *(const half8*)(yn + ((size_t)gy * 128 + gx) * 128 + h * 32 + ch * 8);
            *(half8*)(&lx[(row * 34 + col) * 40 + ch * 8]) = v;
        }
        __syncthreads();
#pragma unroll
        for (int tap = 0; tap < 9; ++tap) {
            const int dy = tap / 3, dx = tap % 3;
            // A: co = mf*16 + l15, k = h*32 + quad*8 + j
            const half_t* wt = wh + tap * (32 * 128) + l15 * 128 + h * 32 + quad * 8;
            half8 a0 = *(const half8*)(wt);
            half8 a1 = *(const half8*)(wt + 16 * 128);
#pragma unroll
            for (int nf = 0; nf < 8; ++nf) {
                int rr = w * 4 + (nf >> 1) + dy;          // row in lx
                int cc = (nf & 1) * 16 + l15 + dx;        // col in lx
                half8 b = *(const half8*)(&lx[(rr * 34 + cc) * 40 + quad * 8]);
                acc[0][nf] = __builtin_amdgcn_mfma_f32_16x16x32_f16(a0, b, acc[0][nf], 0, 0, 0);
                acc[1][nf] = __builtin_amdgcn_mfma_f32_16x16x32_f16(a1, b, acc[1][nf], 0, 0, 0);
            }
        }
        __syncthreads();
    }

    // C/D 16x16: col(px)=l15, row(co local)=quad*4+reg
#pragma unroll
    for (int mf = 0; mf < 2; ++mf) {
        int co0 = mf * 16 + quad * 4;
        floatx4 bv = *(const floatx4*)(bias + co0);
#pragma unroll
        for (int nf = 0; nf < 8; ++nf) {
            int oy = y0 + w * 4 + (nf >> 1), ox = x0 + (nf & 1) * 16 + l15;
            floatx4 A = acc[mf][nf];
            half4_t o;
            o.x = (half_t)fmaxf(A.x + bv.x, 0.f);
            o.y = (half_t)fmaxf(A.y + bv.y, 0.f);
            o.z = (half_t)fmaxf(A.z + bv.z, 0.f);
            o.w = (half_t)fmaxf(A.w + bv.w, 0.f);
            *(half4_t*)(y2h + (((size_t)n * 128 + oy) * 128 + ox) * 32 + co0) = o;
        }
    }
}

// ---------- bilinear x2 (half-pixel centers, clamp edge), NHWC fp16 ----------
__global__ __launch_bounds__(256) void upsample_k(
    const half_t* __restrict__ y2h, half_t* __restrict__ uh)
{
    int idx = blockIdx.x * 256 + threadIdx.x;
    int X = idx & 255, Y = (idx >> 8) & 255, n = idx >> 16;
    int jx = X >> 1, jy = Y >> 1;
    int jxo = (X & 1) ? (jx < 127 ? jx + 1 : 127) : (jx > 0 ? jx - 1 : 0);
    int jyo = (Y & 1) ? (jy < 127 ? jy + 1 : 127) : (jy > 0 ? jy - 1 : 0);
    const half_t* base = y2h + (size_t)n * (128 * 128 * 32);
    const half_t* p00 = base + ((size_t)jy  * 128 + jx ) * 32;
    const half_t* p01 = base + ((size_t)jy  * 128 + jxo) * 32;
    const half_t* p10 = base + ((size_t)jyo * 128 + jx ) * 32;
    const half_t* p11 = base + ((size_t)jyo * 128 + jxo) * 32;
    half_t* op = uh + (((size_t)n * 256 + Y) * 256 + X) * 32;
#pragma unroll
    for (int c = 0; c < 4; ++c) {
        half8 v00 = *(const half8*)(p00 + c * 8);
        half8 v01 = *(const half8*)(p01 + c * 8);
        half8 v10 = *(const half8*)(p10 + c * 8);
        half8 v11 = *(const half8*)(p11 + c * 8);
        half8 o = v00 * (half_t)0.5625f + (v01 + v10) * (half_t)0.1875f
                + v11 * (half_t)0.0625f;
        *(half8*)(op + c * 8) = o;
    }
}

// ---------- conv3: 32->1, fp32 out, v_dot2_f32_f16 ----------
// grid (8, 32, 48): block = 32w x 8h out px, thread = 1 px.
__global__ __launch_bounds__(256) void conv3_k(
    const half_t* __restrict__ uh,   // [n][256][256][32]
    const half_t* __restrict__ wh3,  // [9][32]
    const float*  __restrict__ bias, // [1]
    float* __restrict__ out)         // [n][256][256]
{
    __shared__ half_t lu[10 * 34 * 40];   // ci pitch 32 pad 40 (bank spread)
    const int tid = threadIdx.x;
    const int c = tid & 31, r = tid >> 5;
    const int x0 = blockIdx.x * 32, y0 = blockIdx.y * 8;
    const int n = blockIdx.z;
    const half_t* un = uh + (size_t)n * (256 * 256 * 32);

    for (int idx = tid; idx < 10 * 34 * 4; idx += 256) {
        int ch = idx & 3;
        int col = (idx >> 2) % 34;
        int row = (idx >> 2) / 34;
        int gx = x0 - 1 + col, gy = y0 - 1 + row;
        half8 v = {};
        if ((unsigned)gx < 256u && (unsigned)gy < 256u)
            v = *(const half8*)(un + ((size_t)gy * 256 + gx) * 32 + ch * 8);
        *(half8*)(&lu[(row * 34 + col) * 40 + ch * 8]) = v;
    }
    __syncthreads();

    float acc = 0.f;
#pragma unroll
    for (int tap = 0; tap < 9; ++tap) {
        const int dy = tap / 3, dx = tap % 3;
        const half_t* lp = &lu[((r + dy) * 34 + c + dx) * 40];
        const half_t* wp = wh3 + tap * 32;
#pragma unroll
        for (int cc = 0; cc < 4; ++cc) {
            half8 v = *(const half8*)(lp + cc * 8);
            half8 w = *(const half8*)(wp + cc * 8);
            acc = __builtin_amdgcn_fdot2(__builtin_shufflevector(v, v, 0, 1),
                                         __builtin_shufflevector(w, w, 0, 1), acc, false);
            acc = __builtin_amdgcn_fdot2(__builtin_shufflevector(v, v, 2, 3),
                                         __builtin_shufflevector(w, w, 2, 3), acc, false);
            acc = __builtin_amdgcn_fdot2(__builtin_shufflevector(v, v, 4, 5),
                                         __builtin_shufflevector(w, w, 4, 5), acc, false);
            acc = __builtin_amdgcn_fdot2(__builtin_shufflevector(v, v, 6, 7),
                                         __builtin_shufflevector(w, w, 6, 7), acc, false);
        }
    }
    out[((size_t)n * 256 + (y0 + r)) * 256 + x0 + c] = acc + bias[0];
}

extern "C" void kernel_launch(void* const* d_in, const int* in_sizes, int n_in,
                              void* d_out, int out_size, void* d_ws, size_t ws_size,
                              hipStream_t stream) {
    const float* x  = (const float*)d_in[0];
    // d_in[1] = to_process (identity arange), d_in[2] = batch_size: unused.
    const float* W1 = (const float*)d_in[3];
    const float* b1 = (const float*)d_in[4];
    const float* W2 = (const float*)d_in[5];
    const float* b2 = (const float*)d_in[6];
    const float* W3 = (const float*)d_in[7];
    const float* b3 = (const float*)d_in[8];
    float* out = (float*)d_out;

    char* ws = (char*)d_ws;
    half_t* xh  = (half_t*)ws;                   // 96 MB, region A
    half_t* uh  = (half_t*)ws;                   // 192 MB, region A (xh dead by then)
    half_t* y1h = (half_t*)(ws + 201326592ull);  // 192 MB, region B
    half_t* y2h = (half_t*)(ws + 402653184ull);  // 48 MB,  region C
    half_t* wh1 = (half_t*)(ws + 452984832ull);  // 9*128*64
    half_t* wh2 = wh1 + 73728;                   // 9*32*128
    half_t* wh3 = wh2 + 36864;                   // 9*32

    repack_w<<<434, 256, 0, stream>>>(W1, W2, W3, wh1, wh2, wh3);
    repack_x<<<dim3(64, 48), 256, 0, stream>>>(x, xh);
    conv1_mfma<<<dim3(4, 16, 48), 256, 0, stream>>>(xh, wh1, b1, y1h);
    conv2_mfma<<<dim3(4, 8, 48), 256, 0, stream>>>(y1h, wh2, b2, y2h);
    upsample_k<<<12288, 256, 0, stream>>>(y2h, uh);
    conv3_k<<<dim3(8, 32, 48), 256, 0, stream>>>(uh, wh3, b3, out);
}